// Round 3
// baseline (1727.730 us; speedup 1.0000x reference)
//
#include <hip/hip_runtime.h>

#define NT 131072
#define ED 128
#define KCB 1024
#define NQ 4

#define MT 128                 // tokens per block
#define NBLK (NT / MT)         // 1024 blocks
#define NCH 64                 // codes per chunk
#define NCHUNKS (KCB / NCH)    // 16
#define PAIR_CAP 1024
#define MARGIN 1.5e-3f

typedef __attribute__((ext_vector_type(8))) short bf16x8;
typedef __attribute__((ext_vector_type(4))) float f32x4;

#define ASG __attribute__((address_space(1)))
#define ASL __attribute__((address_space(3)))
#define GLOAD_LDS16(g, l) \
    __builtin_amdgcn_global_load_lds((const ASG void*)(g), (ASL void*)(l), 16, 0, 0)

// ---- bf16 round-to-nearest-even, returns low 16 bits ----
__device__ __forceinline__ unsigned bf16rne(float f) {
    unsigned u = __float_as_uint(f);
    u += 0x7fffu + ((u >> 16) & 1u);
    return u >> 16;
}
__device__ __forceinline__ unsigned packbf(float a, float b) {
    return bf16rne(a) | (bf16rne(b) << 16);
}
// ---- monotone float->uint (unsigned compare preserves float order) ----
__device__ __forceinline__ unsigned fmono(float f) {
    unsigned u = __float_as_uint(f);
    return (u & 0x80000000u) ? ~u : (u | 0x80000000u);
}
// ---- non-temporal float4 load/store via native clang vector (compile fix:
// the builtin rejects HIP_vector_type*, accepts ext_vector_type*) ----
__device__ __forceinline__ float4 ldnt4(const float* p) {
    f32x4 v = __builtin_nontemporal_load((const f32x4*)p);
    float4 r; r.x = v.x; r.y = v.y; r.z = v.z; r.w = v.w;
    return r;
}
__device__ __forceinline__ void stnt4(float* p, float4 v) {
    f32x4 t; t.x = v.x; t.y = v.y; t.z = v.z; t.w = v.w;
    __builtin_nontemporal_store(t, (f32x4*)p);
}

// ---------------------------------------------------------------------------
// prep: cnorm[c] = np.sum(cb*cb, axis=1) fp32 numpy-pairwise (validated r3);
// zero the loss slot.
// ---------------------------------------------------------------------------
__global__ void prep_kernel(const float* __restrict__ cb,
                            float* __restrict__ cnorm,
                            float* __restrict__ loss_slot) {
#pragma clang fp contract(off)
    int c = blockIdx.x * 256 + threadIdx.x;   // 0..4095
    if (blockIdx.x == 0 && threadIdx.x == 0) loss_slot[0] = 0.0f;
    const float* row = cb + (size_t)c * ED;
    float r8[8];
#pragma unroll
    for (int m = 0; m < 8; ++m) { float v = row[m]; r8[m] = v * v; }
    for (int i = 8; i < ED; i += 8) {
#pragma unroll
        for (int m = 0; m < 8; ++m) {
            float v = row[i + m];
            float p = v * v;
            r8[m] = r8[m] + p;
        }
    }
    cnorm[c] = ((r8[0] + r8[1]) + (r8[2] + r8[3]))
             + ((r8[4] + r8[5]) + (r8[6] + r8[7]));
}

// ---------------------------------------------------------------------------
// cvt: pre-convert codebooks to bf16 (same RNE -> bit-identical MFMA inputs)
// into a swizzled, chunk-linear image for pure global_load_lds staging.
// Layout: image (q*16+chunk) of 16384 B; within: row*256 + ((j^(row&7))<<4).
// ---------------------------------------------------------------------------
__global__ void cvt_kernel(const float* __restrict__ cb,
                           unsigned char* __restrict__ cbb) {
#pragma clang fp contract(off)
    int id = blockIdx.x * 256 + threadIdx.x;        // 0..65535
    int rg = id >> 4;                               // global code row 0..4095
    int j  = id & 15;                               // 16B block within row
    const float* src = cb + (size_t)rg * ED + j * 8;
    float4 a = *(const float4*)(src);
    float4 b = *(const float4*)(src + 4);
    uint4 w;
    w.x = packbf(a.x, a.y); w.y = packbf(a.z, a.w);
    w.z = packbf(b.x, b.y); w.w = packbf(b.z, b.w);
    size_t dst = ((size_t)(rg >> 6) << 14)          // 16 KiB chunk image
               + (size_t)((rg & 63) << 8)           // row * 256 B
               + (size_t)((j ^ (rg & 7)) << 4);     // swizzled 16B slot
    *(uint4*)(cbb + dst) = w;
}

// ---------------------------------------------------------------------------
// per-element straight-through chain step (validated r3): given r and code val
// q: d1=fl(q-r); qt=fl(r+d1); rn=fl(r-qt)
#define CHAIN4(V, C)                                                     \
    { float d1x = (C).x - (V).x, d1y = (C).y - (V).y,                    \
            d1z = (C).z - (V).z, d1w = (C).w - (V).w;                    \
      float qtx = (V).x + d1x, qty = (V).y + d1y,                        \
            qtz = (V).z + d1z, qtw = (V).w + d1w;                        \
      (V).x = (V).x - qtx; (V).y = (V).y - qty;                          \
      (V).z = (V).z - qtz; (V).w = (V).w - qtw; }

// ---------------------------------------------------------------------------
// one RVQ stage, Q = compile-time stage index (static history loops ->
// registers, full unroll; arithmetic byte-identical to the validated code)
// ---------------------------------------------------------------------------
template<int Q>
__device__ __forceinline__ void run_stage(
    const float* __restrict__ x, const float* __restrict__ cb,
    const float* __restrict__ cnorm, const unsigned char* __restrict__ cbb,
    float* __restrict__ d_out,
    unsigned char* U, unsigned long long* selMin, float* Ss,
    unsigned short* selSh, unsigned* pairList, int* pairCnt,
    int tid, int lane, int wid, int l15, int quad, int t0, unsigned xorT) {
#pragma clang fp contract(off)
    const float* cbq = cb + (size_t)Q * KCB * ED;
    const unsigned char* cbbq = cbb + ((size_t)Q << 18);  // Q*16 images

    if (tid < MT) selMin[tid] = ~0ull;
    if (tid == 0) *pairCnt = 0;
    __syncthreads();   // also orders prev-stage U reads vs writes below

    // ---- S (numpy pairwise) + As bf16 (swizzled), residual recomputed
    //      from x + selection history (exact fp32 chain, r3-validated) ----
    if (tid < MT) {
        int t = tid;
        const float* xr = x + (size_t)(t0 + t) * ED;
        const float* hp[Q > 0 ? Q : 1];
#pragma unroll
        for (int p2 = 0; p2 < Q; ++p2)
            hp[p2] = cb + ((size_t)p2 * KCB + (int)selSh[t * NQ + p2]) * ED;
        unsigned char* Aw = U + t * 256;
        unsigned xw = (unsigned)((t & 7) << 4);
        float r8[8];
#pragma unroll
        for (int m = 0; m < 8; ++m) r8[m] = 0.f;
#pragma unroll 4
        for (int i = 0; i < 32; ++i) {
            float4 v = ldnt4(xr + (i << 2));
#pragma unroll
            for (int p2 = 0; p2 < Q; ++p2) {
                float4 c = *(const float4*)(hp[p2] + (i << 2));
                CHAIN4(v, c)
            }
            // pack to As (bf16 RNE), 16B-slot XOR swizzle
            uint2 w2;
            w2.x = packbf(v.x, v.y); w2.y = packbf(v.z, v.w);
            *(uint2*)(Aw + (((((unsigned)(i >> 1)) << 4) ^ xw)
                            | ((unsigned)(i & 1) << 3))) = w2;
            // numpy 8-acc squares: k=4i+j -> m=(4i+j)&7
            int base = (i & 1) << 2;
            float px = v.x * v.x, py = v.y * v.y,
                  pz = v.z * v.z, pw = v.w * v.w;
            r8[base + 0] = r8[base + 0] + px;
            r8[base + 1] = r8[base + 1] + py;
            r8[base + 2] = r8[base + 2] + pz;
            r8[base + 3] = r8[base + 3] + pw;
        }
        Ss[t] = ((r8[0] + r8[1]) + (r8[2] + r8[3]))
              + ((r8[4] + r8[5]) + (r8[6] + r8[7]));
    }
    __syncthreads();   // As, Ss ready

    // ---- load token (B-operand) fragments once per stage ----
    bf16x8 bfrag[2][4];
#pragma unroll
    for (int tt = 0; tt < 2; ++tt)
#pragma unroll
        for (int ks = 0; ks < 4; ++ks) {
            int tok = wid * 32 + tt * 16 + l15;
            bfrag[tt][ks] = *(const bf16x8*)(U + tok * 256 +
                (((unsigned)(ks * 64 + quad * 16)) ^ xorT));
        }
    __syncthreads();   // all As reads done -> U becomes Bs buffers

    // ---- stage chunk 0 into buf 0 (DMA; drained at iter-0 counted wait) ----
    {
        const unsigned char* src = cbbq + (wid << 12) + (lane << 4);
        unsigned char* dst = U + (wid << 12) + (lane << 4);
        GLOAD_LDS16(src,        dst);
        GLOAD_LDS16(src + 1024, dst + 1024);
        GLOAD_LDS16(src + 2048, dst + 2048);
        GLOAD_LDS16(src + 3072, dst + 3072);
    }

    // ---- chunk loop: double-buffered Bs, counted-vmcnt pipeline (T4) ----
    // FIFO per iter: [P(cc) x4 (old)] [cnr x4] [P(cc+1) x4 (stays in flight)]
    float rmin[2] = {1e30f, 1e30f};   // per-token running min (wave-private)
    for (int cc = 0; cc < NCHUNKS; ++cc) {
        const int cur = cc & 1;

        // [1] separate prev compute's reads of buf(cur^1) from its overwrite
        __builtin_amdgcn_s_barrier();
        __builtin_amdgcn_sched_barrier(0);

        // cnr loads FIRST (FIFO-older than the prefetch -> their auto-wait
        // is vmcnt(4) and never drains the in-flight prefetch)
        f32x4 cnr[4];
#pragma unroll
        for (int ct = 0; ct < 4; ++ct)
            cnr[ct] = *(const f32x4*)(cnorm + Q * KCB + cc * NCH
                                      + ct * 16 + quad * 4);
        __builtin_amdgcn_sched_barrier(0);

        // prefetch next chunk into the other buffer; stays in flight
        // across barrier [5] and the whole compute phase
        if (cc + 1 < NCHUNKS) {
            const unsigned char* src = cbbq + ((size_t)(cc + 1) << 14)
                                     + (wid << 12) + (lane << 4);
            unsigned char* dst = U + ((cur ^ 1) << 14)
                               + (wid << 12) + (lane << 4);
            GLOAD_LDS16(src,        dst);
            GLOAD_LDS16(src + 1024, dst + 1024);
            GLOAD_LDS16(src + 2048, dst + 2048);
            GLOAD_LDS16(src + 3072, dst + 3072);
            __builtin_amdgcn_sched_barrier(0);
            // drain own P(cc) only: leaves cnr(1)+P(cc+1)(4) outstanding
            asm volatile("s_waitcnt vmcnt(5)" ::: "memory");
        } else {
            __builtin_amdgcn_sched_barrier(0);
            // drain own P(15); leaves cnr outstanding
            asm volatile("s_waitcnt vmcnt(1)" ::: "memory");
        }
        // [5] all waves' P(cc) landed -> buf(cur) fully resident
        __builtin_amdgcn_s_barrier();
        __builtin_amdgcn_sched_barrier(0);

        // MFMA: D[code][token] over 64 codes x 32 tokens per wave
        f32x4 acc[4][2];
#pragma unroll
        for (int ct = 0; ct < 4; ++ct)
#pragma unroll
            for (int tt = 0; tt < 2; ++tt)
                acc[ct][tt] = (f32x4){0.f, 0.f, 0.f, 0.f};
        const unsigned char* Ub = U + (cur << 14);
#pragma unroll
        for (int ks = 0; ks < 4; ++ks) {
            bf16x8 afr[4];
#pragma unroll
            for (int ct = 0; ct < 4; ++ct)
                afr[ct] = *(const bf16x8*)(Ub + (ct * 16 + l15) * 256 +
                    (((unsigned)(ks * 64 + quad * 16)) ^ xorT));
#pragma unroll
            for (int ct = 0; ct < 4; ++ct)
#pragma unroll
                for (int tt = 0; tt < 2; ++tt)
                    acc[ct][tt] = __builtin_amdgcn_mfma_f32_16x16x32_bf16(
                        afr[ct], bfrag[tt][ks], acc[ct][tt], 0, 0, 0);
        }

        // scores e = cn - 2*M~ (approx; exact handled by rescore) + min
        float tmin[2] = {1e30f, 1e30f};
#pragma unroll
        for (int ct = 0; ct < 4; ++ct) {
            f32x4 cn4 = cnr[ct];
#pragma unroll
            for (int tt = 0; tt < 2; ++tt)
#pragma unroll
                for (int r2 = 0; r2 < 4; ++r2) {
                    float m2 = acc[ct][tt][r2];
                    float e = cn4[r2] - (m2 + m2);
                    acc[ct][tt][r2] = e;
                    tmin[tt] = fminf(tmin[tt], e);
                }
        }
#pragma unroll
        for (int tt = 0; tt < 2; ++tt) {
            float v = tmin[tt];
            v = fminf(v, __shfl_xor(v, 16, 64));
            v = fminf(v, __shfl_xor(v, 32, 64));
            rmin[tt] = fminf(rmin[tt], v);   // all lanes hold token min
        }

        // candidate pass for THIS chunk (threshold incl. own chunk)
#pragma unroll
        for (int tt = 0; tt < 2; ++tt) {
            int token = wid * 32 + tt * 16 + l15;
            float th = rmin[tt] + MARGIN;
#pragma unroll
            for (int ct = 0; ct < 4; ++ct)
#pragma unroll
                for (int r2 = 0; r2 < 4; ++r2) {
                    float e = acc[ct][tt][r2];
                    if (e <= th) {
                        int code = cc * NCH + ct * 16 + quad * 4 + r2;
                        int pos = atomicAdd(pairCnt, 1);
                        if (pos < PAIR_CAP)
                            pairList[pos] =
                                ((unsigned)token << 10) | (unsigned)code;
                    }
                }
        }
    }
    __syncthreads();   // full drain; all candidate pushes visible

    // ---- exact rescore of candidates (bit-identical to r3 math) ----
    {
        int npair = *pairCnt < PAIR_CAP ? *pairCnt : PAIR_CAP;
        for (int p = tid; p < npair; p += 256) {
            unsigned pk = pairList[p];
            int t = (pk >> 10) & 127, code = pk & 1023;
            const float* xr = x + (size_t)(t0 + t) * ED;
            const float* cr = cbq + (size_t)code * ED;
            const float* hp[Q > 0 ? Q : 1];
#pragma unroll
            for (int p2 = 0; p2 < Q; ++p2)
                hp[p2] = cb + ((size_t)p2 * KCB + (int)selSh[t * NQ + p2]) * ED;
            float M = 0.f;
            for (int k = 0; k < ED; k += 4) {
                float4 v = ldnt4(xr + k);
#pragma unroll
                for (int p2 = 0; p2 < Q; ++p2) {
                    float4 c = *(const float4*)(hp[p2] + k);
                    CHAIN4(v, c)
                }
                float4 cv = *(const float4*)(cr + k);
                M = fmaf(v.x, cv.x, M); M = fmaf(v.y, cv.y, M);
                M = fmaf(v.z, cv.z, M); M = fmaf(v.w, cv.w, M);
            }
            float t1 = Ss[t] - (M + M);             // rounded (contract off)
            float dd = t1 + cnorm[Q * KCB + code];  // rounded
            unsigned long long key =
                ((unsigned long long)fmono(dd) << 10) | (unsigned)code;
            unsigned long long old = selMin[t];
            while (key < old) {
                unsigned long long assumed = old;
                old = atomicCAS(&selMin[t], assumed, key);
                if (old == assumed) break;
            }
        }
    }
    __syncthreads();

    if (tid < MT) {
        int code = (int)(selMin[tid] & 1023ull);
        selSh[tid * NQ + Q] = (unsigned short)code;
        d_out[(size_t)NT * ED + 1 + (size_t)(t0 + tid) * NQ + Q] = (float)code;
    }
    __syncthreads();
}

// ---------------------------------------------------------------------------
// main fused MFMA RVQ kernel
// out: [0, NT*ED) x_q | [NT*ED] loss | [NT*ED+1 ...) indices (as f32)
// LDS ~39 KB -> 4 blocks/CU (whole grid resident: 1024 blocks = 256CU x 4)
// ---------------------------------------------------------------------------
__global__ __launch_bounds__(256, 4) void rvq_mfma(const float* __restrict__ x,
                                                   const float* __restrict__ cb,
                                                   const float* __restrict__ cnorm,
                                                   const unsigned char* __restrict__ cbb,
                                                   float* __restrict__ d_out) {
#pragma clang fp contract(off)
    // U: union of As (128 tokens x 256 B, swizzled) and Bs double buffer
    // (2 x 16384 B). As is dead once bfrag registers are loaded per stage.
    __shared__ __align__(16) unsigned char U[32768];
    __shared__ unsigned long long selMin[MT];
    __shared__ float    Ss[MT];
    __shared__ unsigned short selSh[MT * NQ];
    __shared__ unsigned pairList[PAIR_CAP];
    __shared__ int      pairCnt;
    __shared__ double   lossW[4];

    const int tid  = threadIdx.x;
    const int lane = tid & 63;
    const int wid  = tid >> 6;     // wave 0..3 -> tokens [wid*32, wid*32+32)
    const int l15  = lane & 15;
    const int quad = lane >> 4;
    const int t0   = blockIdx.x * MT;
    const unsigned xorT = (unsigned)((l15 & 7) << 4);

    run_stage<0>(x, cb, cnorm, cbb, d_out, U, selMin, Ss, selSh,
                 pairList, &pairCnt, tid, lane, wid, l15, quad, t0, xorT);
    run_stage<1>(x, cb, cnorm, cbb, d_out, U, selMin, Ss, selSh,
                 pairList, &pairCnt, tid, lane, wid, l15, quad, t0, xorT);
    run_stage<2>(x, cb, cnorm, cbb, d_out, U, selMin, Ss, selSh,
                 pairList, &pairCnt, tid, lane, wid, l15, quad, t0, xorT);
    run_stage<3>(x, cb, cnorm, cbb, d_out, U, selMin, Ss, selSh,
                 pairList, &pairCnt, tid, lane, wid, l15, quad, t0, xorT);

    // ---- epilogue: x_q = x - r4 (exact chain), loss = sum ||r_1..4||^2 ----
    double lossTot = 0.0;
    if (tid < MT) {
        int t = tid;
        const float* xr = x + (size_t)(t0 + t) * ED;
        const float* hp[4];
#pragma unroll
        for (int p2 = 0; p2 < NQ; ++p2)
            hp[p2] = cb + ((size_t)p2 * KCB + (int)selSh[t * NQ + p2]) * ED;
        double lo = 0.0;
        for (int k = 0; k < ED; k += 4) {
            float4 v = ldnt4(xr + k);
            float4 o = v;
#pragma unroll
            for (int p2 = 0; p2 < NQ; ++p2) {
                float4 c = *(const float4*)(hp[p2] + k);
                CHAIN4(v, c)
                lo += (double)v.x * v.x + (double)v.y * v.y
                    + (double)v.z * v.z + (double)v.w * v.w;
            }
            float4 xq;
            xq.x = o.x - v.x; xq.y = o.y - v.y;
            xq.z = o.z - v.z; xq.w = o.w - v.w;
            stnt4(d_out + (size_t)(t0 + t) * ED + k, xq);
        }
        lossTot = lo;
    }

    // loss reduce: wave shuffle -> LDS -> one atomic per block
    double l = lossTot;
#pragma unroll
    for (int off = 32; off > 0; off >>= 1) l += __shfl_down(l, off, 64);
    if ((tid & 63) == 0) lossW[tid >> 6] = l;
    __syncthreads();
    if (tid == 0) {
        double s = lossW[0] + lossW[1] + lossW[2] + lossW[3];
        // mean_loss = BETA/(4*N*E) * sum_q ||r_{q+1}||^2
        atomicAdd(d_out + (size_t)NT * ED, (float)(s * (0.25 / (4.0 * (double)NT * ED))));
    }
}

// ---------------------------------------------------------------------------
// workspace layout: [0,16KB) cnorm | [16KB, 16KB+1MB) bf16 swizzled codebook
// ---------------------------------------------------------------------------
extern "C" void kernel_launch(void* const* d_in, const int* in_sizes, int n_in,
                              void* d_out, int out_size, void* d_ws, size_t ws_size,
                              hipStream_t stream) {
    const float* x  = (const float*)d_in[0];
    const float* cb = (const float*)d_in[1];
    float* out   = (float*)d_out;
    float* cnorm = (float*)d_ws;                          // 4096 floats
    unsigned char* cbb = (unsigned char*)d_ws + 16384;    // 1 MiB bf16 images

    prep_kernel<<<16, 256, 0, stream>>>(cb, cnorm, out + (size_t)NT * ED);
    cvt_kernel<<<256, 256, 0, stream>>>(cb, cbb);
    rvq_mfma<<<NBLK, 256, 0, stream>>>(x, cb, cnorm, cbb, out);
}

// Round 4
// 1041.793 us; speedup vs baseline: 1.6584x; 1.6584x over previous
//
#include <hip/hip_runtime.h>

#define NT 131072
#define ED 128
#define KCB 1024
#define NQ 4

#define MT 128                 // tokens per block
#define NBLK (NT / MT)         // 1024 blocks
#define NCH 64                 // codes per chunk
#define NCHUNKS (KCB / NCH)    // 16
#define PAIR_CAP 1024
#define MARGIN 1.5e-3f

typedef __attribute__((ext_vector_type(8))) short bf16x8;
typedef __attribute__((ext_vector_type(4))) float f32x4;

#define ASG __attribute__((address_space(1)))
#define ASL __attribute__((address_space(3)))
#define GLOAD_LDS16(g, l) \
    __builtin_amdgcn_global_load_lds((const ASG void*)(g), (ASL void*)(l), 16, 0, 0)

// ---- bf16 round-to-nearest-even, returns low 16 bits ----
__device__ __forceinline__ unsigned bf16rne(float f) {
    unsigned u = __float_as_uint(f);
    u += 0x7fffu + ((u >> 16) & 1u);
    return u >> 16;
}
__device__ __forceinline__ unsigned packbf(float a, float b) {
    return bf16rne(a) | (bf16rne(b) << 16);
}
// ---- monotone float->uint (unsigned compare preserves float order) ----
__device__ __forceinline__ unsigned fmono(float f) {
    unsigned u = __float_as_uint(f);
    return (u & 0x80000000u) ? ~u : (u | 0x80000000u);
}

// ---------------------------------------------------------------------------
// prep: cnorm[c] = np.sum(cb*cb, axis=1) fp32 numpy-pairwise (validated r3);
// zero the loss slot.
// ---------------------------------------------------------------------------
__global__ void prep_kernel(const float* __restrict__ cb,
                            float* __restrict__ cnorm,
                            float* __restrict__ loss_slot) {
#pragma clang fp contract(off)
    int c = blockIdx.x * 256 + threadIdx.x;   // 0..4095
    if (blockIdx.x == 0 && threadIdx.x == 0) loss_slot[0] = 0.0f;
    const float* row = cb + (size_t)c * ED;
    float r8[8];
#pragma unroll
    for (int m = 0; m < 8; ++m) { float v = row[m]; r8[m] = v * v; }
    for (int i = 8; i < ED; i += 8) {
#pragma unroll
        for (int m = 0; m < 8; ++m) {
            float v = row[i + m];
            float p = v * v;
            r8[m] = r8[m] + p;
        }
    }
    cnorm[c] = ((r8[0] + r8[1]) + (r8[2] + r8[3]))
             + ((r8[4] + r8[5]) + (r8[6] + r8[7]));
}

// ---------------------------------------------------------------------------
// cvt: pre-convert codebooks to bf16 (same RNE -> bit-identical MFMA inputs)
// into a swizzled, chunk-linear image for pure global_load_lds staging.
// Layout: image (q*16+chunk) of 16384 B; within: row*256 + ((j^(row&7))<<4).
// ---------------------------------------------------------------------------
__global__ void cvt_kernel(const float* __restrict__ cb,
                           unsigned char* __restrict__ cbb) {
#pragma clang fp contract(off)
    int id = blockIdx.x * 256 + threadIdx.x;        // 0..65535
    int rg = id >> 4;                               // global code row 0..4095
    int j  = id & 15;                               // 16B block within row
    const float* src = cb + (size_t)rg * ED + j * 8;
    float4 a = *(const float4*)(src);
    float4 b = *(const float4*)(src + 4);
    uint4 w;
    w.x = packbf(a.x, a.y); w.y = packbf(a.z, a.w);
    w.z = packbf(b.x, b.y); w.w = packbf(b.z, b.w);
    size_t dst = ((size_t)(rg >> 6) << 14)          // 16 KiB chunk image
               + (size_t)((rg & 63) << 8)           // row * 256 B
               + (size_t)((j ^ (rg & 7)) << 4);     // swizzled 16B slot
    *(uint4*)(cbb + dst) = w;
}

// ---------------------------------------------------------------------------
// per-element straight-through chain step (validated r3): given r and code val
// q: d1=fl(q-r); qt=fl(r+d1); rn=fl(r-qt)
#define CHAIN4(V, C)                                                     \
    { float d1x = (C).x - (V).x, d1y = (C).y - (V).y,                    \
            d1z = (C).z - (V).z, d1w = (C).w - (V).w;                    \
      float qtx = (V).x + d1x, qty = (V).y + d1y,                        \
            qtz = (V).z + d1z, qtw = (V).w + d1w;                        \
      (V).x = (V).x - qtx; (V).y = (V).y - qty;                          \
      (V).z = (V).z - qtz; (V).w = (V).w - qtw; }

// ---------------------------------------------------------------------------
// one RVQ stage, Q = compile-time stage index (static history loops ->
// registers, full unroll; arithmetic byte-identical to the validated code)
// ---------------------------------------------------------------------------
template<int Q>
__device__ __forceinline__ void run_stage(
    const float* __restrict__ x, const float* __restrict__ cb,
    const float* __restrict__ cnorm, const unsigned char* __restrict__ cbb,
    float* __restrict__ d_out,
    unsigned char* U, unsigned long long* selMin, float* Ss,
    unsigned short* selSh, unsigned* pairList, int* pairCnt,
    int tid, int lane, int wid, int l15, int quad, int t0, unsigned xorT) {
#pragma clang fp contract(off)
    const float* cbq = cb + (size_t)Q * KCB * ED;
    const unsigned char* cbbq = cbb + ((size_t)Q << 18);  // Q*16 images

    if (tid < MT) selMin[tid] = ~0ull;
    if (tid == 0) *pairCnt = 0;
    __syncthreads();   // also orders prev-stage U reads vs writes below

    // ---- S (numpy pairwise) + As bf16 (swizzled), residual recomputed
    //      from x + selection history (exact fp32 chain, r3-validated) ----
    if (tid < MT) {
        int t = tid;
        const float* xr = x + (size_t)(t0 + t) * ED;
        const float* hp[Q > 0 ? Q : 1];
#pragma unroll
        for (int p2 = 0; p2 < Q; ++p2)
            hp[p2] = cb + ((size_t)p2 * KCB + (int)selSh[t * NQ + p2]) * ED;
        unsigned char* Aw = U + t * 256;
        unsigned xw = (unsigned)((t & 7) << 4);
        float r8[8];
#pragma unroll
        for (int m = 0; m < 8; ++m) r8[m] = 0.f;
#pragma unroll 4
        for (int i = 0; i < 32; ++i) {
            float4 v = *(const float4*)(xr + (i << 2));
#pragma unroll
            for (int p2 = 0; p2 < Q; ++p2) {
                float4 c = *(const float4*)(hp[p2] + (i << 2));
                CHAIN4(v, c)
            }
            // pack to As (bf16 RNE), 16B-slot XOR swizzle
            uint2 w2;
            w2.x = packbf(v.x, v.y); w2.y = packbf(v.z, v.w);
            *(uint2*)(Aw + (((((unsigned)(i >> 1)) << 4) ^ xw)
                            | ((unsigned)(i & 1) << 3))) = w2;
            // numpy 8-acc squares: k=4i+j -> m=(4i+j)&7
            int base = (i & 1) << 2;
            float px = v.x * v.x, py = v.y * v.y,
                  pz = v.z * v.z, pw = v.w * v.w;
            r8[base + 0] = r8[base + 0] + px;
            r8[base + 1] = r8[base + 1] + py;
            r8[base + 2] = r8[base + 2] + pz;
            r8[base + 3] = r8[base + 3] + pw;
        }
        Ss[t] = ((r8[0] + r8[1]) + (r8[2] + r8[3]))
              + ((r8[4] + r8[5]) + (r8[6] + r8[7]));
    }
    __syncthreads();   // As, Ss ready

    // ---- load token (B-operand) fragments once per stage ----
    bf16x8 bfrag[2][4];
#pragma unroll
    for (int tt = 0; tt < 2; ++tt)
#pragma unroll
        for (int ks = 0; ks < 4; ++ks) {
            int tok = wid * 32 + tt * 16 + l15;
            bfrag[tt][ks] = *(const bf16x8*)(U + tok * 256 +
                (((unsigned)(ks * 64 + quad * 16)) ^ xorT));
        }
    __syncthreads();   // all As reads done -> U becomes Bs buffers

    // ---- stage chunk 0 into buf 0 (DMA; drained at iter-0 counted wait) ----
    {
        const unsigned char* src = cbbq + (wid << 12) + (lane << 4);
        unsigned char* dst = U + (wid << 12) + (lane << 4);
        GLOAD_LDS16(src,        dst);
        GLOAD_LDS16(src + 1024, dst + 1024);
        GLOAD_LDS16(src + 2048, dst + 2048);
        GLOAD_LDS16(src + 3072, dst + 3072);
    }

    // ---- chunk loop: double-buffered Bs, counted-vmcnt pipeline (T4) ----
    // FIFO per iter: [P(cc) x4 (old)] [cnr x4] [P(cc+1) x4 (stays in flight)]
    float rmin[2] = {1e30f, 1e30f};   // per-token running min (wave-private)
    for (int cc = 0; cc < NCHUNKS; ++cc) {
        const int cur = cc & 1;

        // [1] separate prev compute's reads of buf(cur^1) from its overwrite
        __builtin_amdgcn_s_barrier();
        __builtin_amdgcn_sched_barrier(0);

        // cnr loads FIRST (FIFO-older than the prefetch -> their auto-wait
        // never drains the in-flight prefetch)
        f32x4 cnr[4];
#pragma unroll
        for (int ct = 0; ct < 4; ++ct)
            cnr[ct] = *(const f32x4*)(cnorm + Q * KCB + cc * NCH
                                      + ct * 16 + quad * 4);
        __builtin_amdgcn_sched_barrier(0);

        // prefetch next chunk into the other buffer; stays in flight
        // across barrier [5] and the whole compute phase
        if (cc + 1 < NCHUNKS) {
            const unsigned char* src = cbbq + ((size_t)(cc + 1) << 14)
                                     + (wid << 12) + (lane << 4);
            unsigned char* dst = U + ((cur ^ 1) << 14)
                               + (wid << 12) + (lane << 4);
            GLOAD_LDS16(src,        dst);
            GLOAD_LDS16(src + 1024, dst + 1024);
            GLOAD_LDS16(src + 2048, dst + 2048);
            GLOAD_LDS16(src + 3072, dst + 3072);
            __builtin_amdgcn_sched_barrier(0);
            // drain own P(cc): leaves P(cc+1) x4 (+1 cnr) outstanding
            asm volatile("s_waitcnt vmcnt(5)" ::: "memory");
        } else {
            __builtin_amdgcn_sched_barrier(0);
            // drain own P(15); leaves 1 cnr outstanding
            asm volatile("s_waitcnt vmcnt(1)" ::: "memory");
        }
        // [5] all waves' P(cc) landed -> buf(cur) fully resident
        __builtin_amdgcn_s_barrier();
        __builtin_amdgcn_sched_barrier(0);

        // MFMA: D[code][token] over 64 codes x 32 tokens per wave
        f32x4 acc[4][2];
#pragma unroll
        for (int ct = 0; ct < 4; ++ct)
#pragma unroll
            for (int tt = 0; tt < 2; ++tt)
                acc[ct][tt] = (f32x4){0.f, 0.f, 0.f, 0.f};
        const unsigned char* Ub = U + (cur << 14);
#pragma unroll
        for (int ks = 0; ks < 4; ++ks) {
            bf16x8 afr[4];
#pragma unroll
            for (int ct = 0; ct < 4; ++ct)
                afr[ct] = *(const bf16x8*)(Ub + (ct * 16 + l15) * 256 +
                    (((unsigned)(ks * 64 + quad * 16)) ^ xorT));
#pragma unroll
            for (int ct = 0; ct < 4; ++ct)
#pragma unroll
                for (int tt = 0; tt < 2; ++tt)
                    acc[ct][tt] = __builtin_amdgcn_mfma_f32_16x16x32_bf16(
                        afr[ct], bfrag[tt][ks], acc[ct][tt], 0, 0, 0);
        }

        // scores e = cn - 2*M~ (approx; exact handled by rescore) + min
        float tmin[2] = {1e30f, 1e30f};
#pragma unroll
        for (int ct = 0; ct < 4; ++ct) {
            f32x4 cn4 = cnr[ct];
#pragma unroll
            for (int tt = 0; tt < 2; ++tt)
#pragma unroll
                for (int r2 = 0; r2 < 4; ++r2) {
                    float m2 = acc[ct][tt][r2];
                    float e = cn4[r2] - (m2 + m2);
                    acc[ct][tt][r2] = e;
                    tmin[tt] = fminf(tmin[tt], e);
                }
        }
#pragma unroll
        for (int tt = 0; tt < 2; ++tt) {
            float v = tmin[tt];
            v = fminf(v, __shfl_xor(v, 16, 64));
            v = fminf(v, __shfl_xor(v, 32, 64));
            rmin[tt] = fminf(rmin[tt], v);   // all lanes hold token min
        }

        // candidate pass for THIS chunk (threshold incl. own chunk)
#pragma unroll
        for (int tt = 0; tt < 2; ++tt) {
            int token = wid * 32 + tt * 16 + l15;
            float th = rmin[tt] + MARGIN;
#pragma unroll
            for (int ct = 0; ct < 4; ++ct)
#pragma unroll
                for (int r2 = 0; r2 < 4; ++r2) {
                    float e = acc[ct][tt][r2];
                    if (e <= th) {
                        int code = cc * NCH + ct * 16 + quad * 4 + r2;
                        int pos = atomicAdd(pairCnt, 1);
                        if (pos < PAIR_CAP)
                            pairList[pos] =
                                ((unsigned)token << 10) | (unsigned)code;
                    }
                }
        }
    }
    __syncthreads();   // full drain; all candidate pushes visible

    // ---- exact rescore of candidates (bit-identical to r3 math) ----
    {
        int npair = *pairCnt < PAIR_CAP ? *pairCnt : PAIR_CAP;
        for (int p = tid; p < npair; p += 256) {
            unsigned pk = pairList[p];
            int t = (pk >> 10) & 127, code = pk & 1023;
            const float* xr = x + (size_t)(t0 + t) * ED;
            const float* cr = cbq + (size_t)code * ED;
            const float* hp[Q > 0 ? Q : 1];
#pragma unroll
            for (int p2 = 0; p2 < Q; ++p2)
                hp[p2] = cb + ((size_t)p2 * KCB + (int)selSh[t * NQ + p2]) * ED;
            float M = 0.f;
            for (int k = 0; k < ED; k += 4) {
                float4 v = *(const float4*)(xr + k);
#pragma unroll
                for (int p2 = 0; p2 < Q; ++p2) {
                    float4 c = *(const float4*)(hp[p2] + k);
                    CHAIN4(v, c)
                }
                float4 cv = *(const float4*)(cr + k);
                M = fmaf(v.x, cv.x, M); M = fmaf(v.y, cv.y, M);
                M = fmaf(v.z, cv.z, M); M = fmaf(v.w, cv.w, M);
            }
            float t1 = Ss[t] - (M + M);             // rounded (contract off)
            float dd = t1 + cnorm[Q * KCB + code];  // rounded
            unsigned long long key =
                ((unsigned long long)fmono(dd) << 10) | (unsigned)code;
            unsigned long long old = selMin[t];
            while (key < old) {
                unsigned long long assumed = old;
                old = atomicCAS(&selMin[t], assumed, key);
                if (old == assumed) break;
            }
        }
    }
    __syncthreads();

    if (tid < MT) {
        int code = (int)(selMin[tid] & 1023ull);
        selSh[tid * NQ + Q] = (unsigned short)code;
        d_out[(size_t)NT * ED + 1 + (size_t)(t0 + tid) * NQ + Q] = (float)code;
    }
    __syncthreads();
}

// ---------------------------------------------------------------------------
// main fused MFMA RVQ kernel
// out: [0, NT*ED) x_q | [NT*ED] loss | [NT*ED+1 ...) indices (as f32)
// LDS ~39 KB. launch_bounds(256,3): allocator budget ~170 VGPR (no spills);
// if the kernel fits <=128 VGPR, LDS still gives 4 blocks/CU residency.
// ---------------------------------------------------------------------------
__global__ __launch_bounds__(256, 3) void rvq_mfma(const float* __restrict__ x,
                                                   const float* __restrict__ cb,
                                                   const float* __restrict__ cnorm,
                                                   const unsigned char* __restrict__ cbb,
                                                   float* __restrict__ d_out) {
#pragma clang fp contract(off)
    // U: union of As (128 tokens x 256 B, swizzled) and Bs double buffer
    // (2 x 16384 B). As is dead once bfrag registers are loaded per stage.
    __shared__ __align__(16) unsigned char U[32768];
    __shared__ unsigned long long selMin[MT];
    __shared__ float    Ss[MT];
    __shared__ unsigned short selSh[MT * NQ];
    __shared__ unsigned pairList[PAIR_CAP];
    __shared__ int      pairCnt;
    __shared__ double   lossW[4];

    const int tid  = threadIdx.x;
    const int lane = tid & 63;
    const int wid  = tid >> 6;     // wave 0..3 -> tokens [wid*32, wid*32+32)
    const int l15  = lane & 15;
    const int quad = lane >> 4;
    const int t0   = blockIdx.x * MT;
    const unsigned xorT = (unsigned)((l15 & 7) << 4);

    run_stage<0>(x, cb, cnorm, cbb, d_out, U, selMin, Ss, selSh,
                 pairList, &pairCnt, tid, lane, wid, l15, quad, t0, xorT);
    run_stage<1>(x, cb, cnorm, cbb, d_out, U, selMin, Ss, selSh,
                 pairList, &pairCnt, tid, lane, wid, l15, quad, t0, xorT);
    run_stage<2>(x, cb, cnorm, cbb, d_out, U, selMin, Ss, selSh,
                 pairList, &pairCnt, tid, lane, wid, l15, quad, t0, xorT);
    run_stage<3>(x, cb, cnorm, cbb, d_out, U, selMin, Ss, selSh,
                 pairList, &pairCnt, tid, lane, wid, l15, quad, t0, xorT);

    // ---- epilogue: x_q = x - r4 (exact chain), loss = sum ||r_1..4||^2 ----
    double lossTot = 0.0;
    if (tid < MT) {
        int t = tid;
        const float* xr = x + (size_t)(t0 + t) * ED;
        const float* hp[4];
#pragma unroll
        for (int p2 = 0; p2 < NQ; ++p2)
            hp[p2] = cb + ((size_t)p2 * KCB + (int)selSh[t * NQ + p2]) * ED;
        double lo = 0.0;
        for (int k = 0; k < ED; k += 4) {
            float4 v = *(const float4*)(xr + k);
            float4 o = v;
#pragma unroll
            for (int p2 = 0; p2 < NQ; ++p2) {
                float4 c = *(const float4*)(hp[p2] + k);
                CHAIN4(v, c)
                lo += (double)v.x * v.x + (double)v.y * v.y
                    + (double)v.z * v.z + (double)v.w * v.w;
            }
            float4 xq;
            xq.x = o.x - v.x; xq.y = o.y - v.y;
            xq.z = o.z - v.z; xq.w = o.w - v.w;
            *(float4*)(d_out + (size_t)(t0 + t) * ED + k) = xq;
        }
        lossTot = lo;
    }

    // loss reduce: wave shuffle -> LDS -> one atomic per block
    double l = lossTot;
#pragma unroll
    for (int off = 32; off > 0; off >>= 1) l += __shfl_down(l, off, 64);
    if ((tid & 63) == 0) lossW[tid >> 6] = l;
    __syncthreads();
    if (tid == 0) {
        double s = lossW[0] + lossW[1] + lossW[2] + lossW[3];
        // mean_loss = BETA/(4*N*E) * sum_q ||r_{q+1}||^2
        atomicAdd(d_out + (size_t)NT * ED, (float)(s * (0.25 / (4.0 * (double)NT * ED))));
    }
}

// ---------------------------------------------------------------------------
// workspace layout: [0,16KB) cnorm | [16KB, 16KB+1MB) bf16 swizzled codebook
// ---------------------------------------------------------------------------
extern "C" void kernel_launch(void* const* d_in, const int* in_sizes, int n_in,
                              void* d_out, int out_size, void* d_ws, size_t ws_size,
                              hipStream_t stream) {
    const float* x  = (const float*)d_in[0];
    const float* cb = (const float*)d_in[1];
    float* out   = (float*)d_out;
    float* cnorm = (float*)d_ws;                          // 4096 floats
    unsigned char* cbb = (unsigned char*)d_ws + 16384;    // 1 MiB bf16 images

    prep_kernel<<<16, 256, 0, stream>>>(cb, cnorm, out + (size_t)NT * ED);
    cvt_kernel<<<256, 256, 0, stream>>>(cb, cbb);
    rvq_mfma<<<NBLK, 256, 0, stream>>>(x, cb, cnorm, cbb, out);
}

// Round 5
// 990.619 us; speedup vs baseline: 1.7441x; 1.0517x over previous
//
#include <hip/hip_runtime.h>

#define NT 131072
#define ED 128
#define KCB 1024
#define NQ 4

#define MT 128                 // tokens per block
#define NBLK (NT / MT)         // 1024 blocks
#define NCH 64                 // codes per chunk
#define NCHUNKS (KCB / NCH)    // 16
#define PAIR_CAP 1024
#define MARGIN 1.5e-3f

#define TRL 16384              // trailer (cnorm slice) offset inside a Bs buf
#define BUFSZ 16640            // 16 KB codes + 256 B cnorm trailer

typedef __attribute__((ext_vector_type(8))) short bf16x8;
typedef __attribute__((ext_vector_type(4))) float f32x4;

#define ASG __attribute__((address_space(1)))
#define ASL __attribute__((address_space(3)))
#define GLOAD_LDS16(g, l) \
    __builtin_amdgcn_global_load_lds((const ASG void*)(g), (ASL void*)(l), 16, 0, 0)

// ---- bf16 round-to-nearest-even, returns low 16 bits ----
__device__ __forceinline__ unsigned bf16rne(float f) {
    unsigned u = __float_as_uint(f);
    u += 0x7fffu + ((u >> 16) & 1u);
    return u >> 16;
}
__device__ __forceinline__ unsigned packbf(float a, float b) {
    return bf16rne(a) | (bf16rne(b) << 16);
}
// ---- monotone float->uint (unsigned compare preserves float order) ----
__device__ __forceinline__ unsigned fmono(float f) {
    unsigned u = __float_as_uint(f);
    return (u & 0x80000000u) ? ~u : (u | 0x80000000u);
}

// ---------------------------------------------------------------------------
// prep: cnorm[c] = np.sum(cb*cb, axis=1) fp32 numpy-pairwise (validated r3);
// zero the loss slot.
// ---------------------------------------------------------------------------
__global__ void prep_kernel(const float* __restrict__ cb,
                            float* __restrict__ cnorm,
                            float* __restrict__ loss_slot) {
#pragma clang fp contract(off)
    int c = blockIdx.x * 256 + threadIdx.x;   // 0..4095
    if (blockIdx.x == 0 && threadIdx.x == 0) loss_slot[0] = 0.0f;
    const float* row = cb + (size_t)c * ED;
    float r8[8];
#pragma unroll
    for (int m = 0; m < 8; ++m) { float v = row[m]; r8[m] = v * v; }
    for (int i = 8; i < ED; i += 8) {
#pragma unroll
        for (int m = 0; m < 8; ++m) {
            float v = row[i + m];
            float p = v * v;
            r8[m] = r8[m] + p;
        }
    }
    cnorm[c] = ((r8[0] + r8[1]) + (r8[2] + r8[3]))
             + ((r8[4] + r8[5]) + (r8[6] + r8[7]));
}

// ---------------------------------------------------------------------------
// cvt: pre-convert codebooks to bf16 (same RNE -> bit-identical MFMA inputs)
// into a swizzled, chunk-linear image for pure global_load_lds staging.
// Layout: image (q*16+chunk) of 16384 B; within: row*256 + ((j^(row&7))<<4).
// ---------------------------------------------------------------------------
__global__ void cvt_kernel(const float* __restrict__ cb,
                           unsigned char* __restrict__ cbb) {
#pragma clang fp contract(off)
    int id = blockIdx.x * 256 + threadIdx.x;        // 0..65535
    int rg = id >> 4;                               // global code row 0..4095
    int j  = id & 15;                               // 16B block within row
    const float* src = cb + (size_t)rg * ED + j * 8;
    float4 a = *(const float4*)(src);
    float4 b = *(const float4*)(src + 4);
    uint4 w;
    w.x = packbf(a.x, a.y); w.y = packbf(a.z, a.w);
    w.z = packbf(b.x, b.y); w.w = packbf(b.z, b.w);
    size_t dst = ((size_t)(rg >> 6) << 14)          // 16 KiB chunk image
               + (size_t)((rg & 63) << 8)           // row * 256 B
               + (size_t)((j ^ (rg & 7)) << 4);     // swizzled 16B slot
    *(uint4*)(cbb + dst) = w;
}

// ---------------------------------------------------------------------------
// per-element straight-through chain step (validated r3): given r and code val
// q: d1=fl(q-r); qt=fl(r+d1); rn=fl(r-qt)
#define CHAIN4(V, C)                                                     \
    { float d1x = (C).x - (V).x, d1y = (C).y - (V).y,                    \
            d1z = (C).z - (V).z, d1w = (C).w - (V).w;                    \
      float qtx = (V).x + d1x, qty = (V).y + d1y,                        \
            qtz = (V).z + d1z, qtw = (V).w + d1w;                        \
      (V).x = (V).x - qtx; (V).y = (V).y - qty;                          \
      (V).z = (V).z - qtz; (V).w = (V).w - qtw; }

// ---------------------------------------------------------------------------
// one RVQ stage, Q = compile-time stage index (static history loops ->
// registers, full unroll; arithmetic byte-identical to the validated code)
// ---------------------------------------------------------------------------
template<int Q>
__device__ __forceinline__ void run_stage(
    const float* __restrict__ x, const float* __restrict__ cb,
    const float* __restrict__ cnorm, const unsigned char* __restrict__ cbb,
    float* __restrict__ d_out,
    unsigned char* U, unsigned long long* selMin, float* Ss,
    unsigned short* selSh, unsigned* pairList, int* pairCnt,
    int tid, int lane, int wid, int l15, int quad, int t0, unsigned xorT) {
#pragma clang fp contract(off)
    const float* cbq = cb + (size_t)Q * KCB * ED;
    const unsigned char* cbbq = cbb + ((size_t)Q << 18);  // Q*16 images
    const float* cnq = cnorm + Q * KCB;

    if (tid < MT) selMin[tid] = ~0ull;
    if (tid == 0) *pairCnt = 0;
    __syncthreads();   // also orders prev-stage U reads vs writes below

    // ---- S (numpy pairwise) + As bf16 (swizzled), residual recomputed
    //      from x + selection history (exact fp32 chain, r3-validated) ----
    if (tid < MT) {
        int t = tid;
        const float* xr = x + (size_t)(t0 + t) * ED;
        const float* hp[Q > 0 ? Q : 1];
#pragma unroll
        for (int p2 = 0; p2 < Q; ++p2)
            hp[p2] = cb + ((size_t)p2 * KCB + (int)selSh[t * NQ + p2]) * ED;
        unsigned char* Aw = U + t * 256;
        unsigned xw = (unsigned)((t & 7) << 4);
        float r8[8];
#pragma unroll
        for (int m = 0; m < 8; ++m) r8[m] = 0.f;
#pragma unroll 4
        for (int i = 0; i < 32; ++i) {
            float4 v = *(const float4*)(xr + (i << 2));
#pragma unroll
            for (int p2 = 0; p2 < Q; ++p2) {
                float4 c = *(const float4*)(hp[p2] + (i << 2));
                CHAIN4(v, c)
            }
            // pack to As (bf16 RNE), 16B-slot XOR swizzle
            uint2 w2;
            w2.x = packbf(v.x, v.y); w2.y = packbf(v.z, v.w);
            *(uint2*)(Aw + (((((unsigned)(i >> 1)) << 4) ^ xw)
                            | ((unsigned)(i & 1) << 3))) = w2;
            // numpy 8-acc squares: k=4i+j -> m=(4i+j)&7
            int base = (i & 1) << 2;
            float px = v.x * v.x, py = v.y * v.y,
                  pz = v.z * v.z, pw = v.w * v.w;
            r8[base + 0] = r8[base + 0] + px;
            r8[base + 1] = r8[base + 1] + py;
            r8[base + 2] = r8[base + 2] + pz;
            r8[base + 3] = r8[base + 3] + pw;
        }
        Ss[t] = ((r8[0] + r8[1]) + (r8[2] + r8[3]))
              + ((r8[4] + r8[5]) + (r8[6] + r8[7]));
    }
    __syncthreads();   // As, Ss ready

    // ---- load token (B-operand) fragments once per stage ----
    bf16x8 bfrag[2][4];
#pragma unroll
    for (int tt = 0; tt < 2; ++tt)
#pragma unroll
        for (int ks = 0; ks < 4; ++ks) {
            int tok = wid * 32 + tt * 16 + l15;
            bfrag[tt][ks] = *(const bf16x8*)(U + tok * 256 +
                (((unsigned)(ks * 64 + quad * 16)) ^ xorT));
        }
    __syncthreads();   // all As reads done -> U becomes Bs buffers

    // ---- stage chunk 0 into buf 0: 4 code DMAs + 1 cnorm-trailer DMA ----
    {
        const unsigned char* src = cbbq + (wid << 12) + (lane << 4);
        unsigned char* dst = U + (wid << 12) + (lane << 4);
        GLOAD_LDS16(src,        dst);
        GLOAD_LDS16(src + 1024, dst + 1024);
        GLOAD_LDS16(src + 2048, dst + 2048);
        GLOAD_LDS16(src + 3072, dst + 3072);
        if (lane < 16)   // 256 B cnorm slice; redundant x4 waves (same bytes)
            GLOAD_LDS16((const unsigned char*)cnq + (lane << 4),
                        U + TRL + (lane << 4));
    }

    // ---- chunk loop: double-buffered Bs, counted-vmcnt pipeline (T4) ----
    // FIFO per wave per iter: [P(cc) x5 (old)] [P(cc+1) x5 (stays in flight)]
    float rmin[2] = {1e30f, 1e30f};   // per-token running min (wave-private)
    for (int cc = 0; cc < NCHUNKS; ++cc) {
        const int cur = cc & 1;

        // [1] separate prev compute's reads of buf(cur^1) from its overwrite
        __builtin_amdgcn_s_barrier();
        __builtin_amdgcn_sched_barrier(0);

        // prefetch next chunk into the other buffer; stays in flight
        // across barrier [5] and the whole compute phase
        if (cc + 1 < NCHUNKS) {
            const unsigned char* src = cbbq + ((size_t)(cc + 1) << 14)
                                     + (wid << 12) + (lane << 4);
            unsigned char* dst = U + (cur ^ 1) * BUFSZ
                               + (wid << 12) + (lane << 4);
            GLOAD_LDS16(src,        dst);
            GLOAD_LDS16(src + 1024, dst + 1024);
            GLOAD_LDS16(src + 2048, dst + 2048);
            GLOAD_LDS16(src + 3072, dst + 3072);
            if (lane < 16)
                GLOAD_LDS16((const unsigned char*)(cnq + (cc + 1) * NCH)
                                + (lane << 4),
                            U + (cur ^ 1) * BUFSZ + TRL + (lane << 4));
            __builtin_amdgcn_sched_barrier(0);
            // drain own P(cc) x5: leaves P(cc+1) x5 outstanding
            asm volatile("s_waitcnt vmcnt(5)" ::: "memory");
        } else {
            __builtin_amdgcn_sched_barrier(0);
            // drain own P(15); nothing else outstanding
            asm volatile("s_waitcnt vmcnt(0)" ::: "memory");
        }
        // [5] all waves' P(cc) landed -> buf(cur) fully resident
        __builtin_amdgcn_s_barrier();
        __builtin_amdgcn_sched_barrier(0);

        // MFMA: D[code][token] over 64 codes x 32 tokens per wave
        f32x4 acc[4][2];
#pragma unroll
        for (int ct = 0; ct < 4; ++ct)
#pragma unroll
            for (int tt = 0; tt < 2; ++tt)
                acc[ct][tt] = (f32x4){0.f, 0.f, 0.f, 0.f};
        const unsigned char* Ub = U + cur * BUFSZ;
#pragma unroll
        for (int ks = 0; ks < 4; ++ks) {
            bf16x8 afr[4];
#pragma unroll
            for (int ct = 0; ct < 4; ++ct)
                afr[ct] = *(const bf16x8*)(Ub + (ct * 16 + l15) * 256 +
                    (((unsigned)(ks * 64 + quad * 16)) ^ xorT));
#pragma unroll
            for (int ct = 0; ct < 4; ++ct)
#pragma unroll
                for (int tt = 0; tt < 2; ++tt)
                    acc[ct][tt] = __builtin_amdgcn_mfma_f32_16x16x32_bf16(
                        afr[ct], bfrag[tt][ks], acc[ct][tt], 0, 0, 0);
        }

        // scores e = cn - 2*M~ (approx; exact handled by rescore) + min
        // cn read from LDS trailer (bit-identical floats, no VMEM in loop)
        const float* cnL = (const float*)(Ub + TRL);
        float tmin[2] = {1e30f, 1e30f};
#pragma unroll
        for (int ct = 0; ct < 4; ++ct) {
            f32x4 cn4 = *(const f32x4*)(cnL + ct * 16 + quad * 4);
#pragma unroll
            for (int tt = 0; tt < 2; ++tt)
#pragma unroll
                for (int r2 = 0; r2 < 4; ++r2) {
                    float m2 = acc[ct][tt][r2];
                    float e = cn4[r2] - (m2 + m2);
                    acc[ct][tt][r2] = e;
                    tmin[tt] = fminf(tmin[tt], e);
                }
        }
#pragma unroll
        for (int tt = 0; tt < 2; ++tt) {
            float v = tmin[tt];
            v = fminf(v, __shfl_xor(v, 16, 64));
            v = fminf(v, __shfl_xor(v, 32, 64));
            rmin[tt] = fminf(rmin[tt], v);   // all lanes hold token min
        }

        // candidate pass for THIS chunk (threshold incl. own chunk)
#pragma unroll
        for (int tt = 0; tt < 2; ++tt) {
            int token = wid * 32 + tt * 16 + l15;
            float th = rmin[tt] + MARGIN;
#pragma unroll
            for (int ct = 0; ct < 4; ++ct)
#pragma unroll
                for (int r2 = 0; r2 < 4; ++r2) {
                    float e = acc[ct][tt][r2];
                    if (e <= th) {
                        int code = cc * NCH + ct * 16 + quad * 4 + r2;
                        int pos = atomicAdd(pairCnt, 1);
                        if (pos < PAIR_CAP)
                            pairList[pos] =
                                ((unsigned)token << 10) | (unsigned)code;
                    }
                }
        }
    }
    __syncthreads();   // all candidate pushes visible

    // ---- exact rescore of candidates (bit-identical to r3 math) ----
    {
        int npair = *pairCnt < PAIR_CAP ? *pairCnt : PAIR_CAP;
        for (int p = tid; p < npair; p += 256) {
            unsigned pk = pairList[p];
            int t = (pk >> 10) & 127, code = pk & 1023;
            const float* xr = x + (size_t)(t0 + t) * ED;
            const float* cr = cbq + (size_t)code * ED;
            const float* hp[Q > 0 ? Q : 1];
#pragma unroll
            for (int p2 = 0; p2 < Q; ++p2)
                hp[p2] = cb + ((size_t)p2 * KCB + (int)selSh[t * NQ + p2]) * ED;
            float M = 0.f;
#pragma unroll 4
            for (int k = 0; k < ED; k += 4) {
                float4 v = *(const float4*)(xr + k);
#pragma unroll
                for (int p2 = 0; p2 < Q; ++p2) {
                    float4 c = *(const float4*)(hp[p2] + k);
                    CHAIN4(v, c)
                }
                float4 cv = *(const float4*)(cr + k);
                M = fmaf(v.x, cv.x, M); M = fmaf(v.y, cv.y, M);
                M = fmaf(v.z, cv.z, M); M = fmaf(v.w, cv.w, M);
            }
            float t1 = Ss[t] - (M + M);             // rounded (contract off)
            float dd = t1 + cnorm[Q * KCB + code];  // rounded
            unsigned long long key =
                ((unsigned long long)fmono(dd) << 10) | (unsigned)code;
            unsigned long long old = selMin[t];
            while (key < old) {
                unsigned long long assumed = old;
                old = atomicCAS(&selMin[t], assumed, key);
                if (old == assumed) break;
            }
        }
    }
    __syncthreads();

    if (tid < MT) {
        int code = (int)(selMin[tid] & 1023ull);
        selSh[tid * NQ + Q] = (unsigned short)code;
        d_out[(size_t)NT * ED + 1 + (size_t)(t0 + tid) * NQ + Q] = (float)code;
    }
    __syncthreads();
}

// ---------------------------------------------------------------------------
// main fused MFMA RVQ kernel
// out: [0, NT*ED) x_q | [NT*ED] loss | [NT*ED+1 ...) indices (as f32)
// LDS ~39.1 KB -> 4 blocks/CU residency (VGPR target <=128, no scratch).
// ---------------------------------------------------------------------------
__global__ __launch_bounds__(256, 3) void rvq_mfma(const float* __restrict__ x,
                                                   const float* __restrict__ cb,
                                                   const float* __restrict__ cnorm,
                                                   const unsigned char* __restrict__ cbb,
                                                   float* __restrict__ d_out) {
#pragma clang fp contract(off)
    // U: union of As (128 tokens x 256 B, swizzled) and Bs double buffer
    // (2 x (16 KB codes + 256 B cnorm trailer)). As dead once bfrag loaded.
    __shared__ __align__(16) unsigned char U[2 * BUFSZ];
    __shared__ unsigned long long selMin[MT];
    __shared__ float    Ss[MT];
    __shared__ unsigned short selSh[MT * NQ];
    __shared__ unsigned pairList[PAIR_CAP];
    __shared__ int      pairCnt;
    __shared__ double   lossW[4];

    const int tid  = threadIdx.x;
    const int lane = tid & 63;
    const int wid  = tid >> 6;     // wave 0..3 -> tokens [wid*32, wid*32+32)
    const int l15  = lane & 15;
    const int quad = lane >> 4;
    const int t0   = blockIdx.x * MT;
    const unsigned xorT = (unsigned)((l15 & 7) << 4);

    run_stage<0>(x, cb, cnorm, cbb, d_out, U, selMin, Ss, selSh,
                 pairList, &pairCnt, tid, lane, wid, l15, quad, t0, xorT);
    run_stage<1>(x, cb, cnorm, cbb, d_out, U, selMin, Ss, selSh,
                 pairList, &pairCnt, tid, lane, wid, l15, quad, t0, xorT);
    run_stage<2>(x, cb, cnorm, cbb, d_out, U, selMin, Ss, selSh,
                 pairList, &pairCnt, tid, lane, wid, l15, quad, t0, xorT);
    run_stage<3>(x, cb, cnorm, cbb, d_out, U, selMin, Ss, selSh,
                 pairList, &pairCnt, tid, lane, wid, l15, quad, t0, xorT);

    // ---- epilogue: x_q = x - r4 (exact chain), loss = sum ||r_1..4||^2 ----
    double lossTot = 0.0;
    if (tid < MT) {
        int t = tid;
        const float* xr = x + (size_t)(t0 + t) * ED;
        const float* hp[4];
#pragma unroll
        for (int p2 = 0; p2 < NQ; ++p2)
            hp[p2] = cb + ((size_t)p2 * KCB + (int)selSh[t * NQ + p2]) * ED;
        double lo = 0.0;
#pragma unroll 4
        for (int k = 0; k < ED; k += 4) {
            float4 v = *(const float4*)(xr + k);
            float4 o = v;
#pragma unroll
            for (int p2 = 0; p2 < NQ; ++p2) {
                float4 c = *(const float4*)(hp[p2] + k);
                CHAIN4(v, c)
                lo += (double)v.x * v.x + (double)v.y * v.y
                    + (double)v.z * v.z + (double)v.w * v.w;
            }
            float4 xq;
            xq.x = o.x - v.x; xq.y = o.y - v.y;
            xq.z = o.z - v.z; xq.w = o.w - v.w;
            *(float4*)(d_out + (size_t)(t0 + t) * ED + k) = xq;
        }
        lossTot = lo;
    }

    // loss reduce: wave shuffle -> LDS -> one atomic per block
    double l = lossTot;
#pragma unroll
    for (int off = 32; off > 0; off >>= 1) l += __shfl_down(l, off, 64);
    if ((tid & 63) == 0) lossW[tid >> 6] = l;
    __syncthreads();
    if (tid == 0) {
        double s = lossW[0] + lossW[1] + lossW[2] + lossW[3];
        // mean_loss = BETA/(4*N*E) * sum_q ||r_{q+1}||^2
        atomicAdd(d_out + (size_t)NT * ED, (float)(s * (0.25 / (4.0 * (double)NT * ED))));
    }
}

// ---------------------------------------------------------------------------
// workspace layout: [0,16KB) cnorm | [16KB, 16KB+1MB) bf16 swizzled codebook
// ---------------------------------------------------------------------------
extern "C" void kernel_launch(void* const* d_in, const int* in_sizes, int n_in,
                              void* d_out, int out_size, void* d_ws, size_t ws_size,
                              hipStream_t stream) {
    const float* x  = (const float*)d_in[0];
    const float* cb = (const float*)d_in[1];
    float* out   = (float*)d_out;
    float* cnorm = (float*)d_ws;                          // 4096 floats
    unsigned char* cbb = (unsigned char*)d_ws + 16384;    // 1 MiB bf16 images

    prep_kernel<<<16, 256, 0, stream>>>(cb, cnorm, out + (size_t)NT * ED);
    cvt_kernel<<<256, 256, 0, stream>>>(cb, cbb);
    rvq_mfma<<<NBLK, 256, 0, stream>>>(x, cb, cnorm, cbb, out);
}